// Round 5
// baseline (590.303 us; speedup 1.0000x reference)
//
#include <hip/hip_runtime.h>
#include <hip/hip_bf16.h>

typedef __attribute__((ext_vector_type(8))) short short8;
typedef __attribute__((ext_vector_type(4))) short short4_t;
typedef __attribute__((ext_vector_type(4))) float float4_t;
typedef unsigned short ushort;

#define HW 4096
#define CC 256
#define NBATCH 4
#define SEQ ((size_t)NBATCH * HW)

static __device__ __forceinline__ unsigned short f2b(float f) {
    union { float f; unsigned u; } v; v.f = f;
    unsigned r = v.u + 0x7FFF + ((v.u >> 16) & 1);   // RNE
    return (unsigned short)(r >> 16);
}

// ---- kernel 1: x[n][c][p] -> XT[n][p][c] (bf16) and gb[n][c][p] (bf16),
//      with fused fp32->bf16 weight conversion (first 768 flat blocks). ----
__global__ __launch_bounds__(256) void k_prep(const float* __restrict__ x,
                                              const float* __restrict__ tw,
                                              const float* __restrict__ pw,
                                              const float* __restrict__ cw,
                                              unsigned short* __restrict__ XT,
                                              unsigned short* __restrict__ gb,
                                              unsigned short* __restrict__ Wbt,
                                              unsigned short* __restrict__ Wbp,
                                              unsigned short* __restrict__ Wbc) {
    __shared__ float T[64][65];
    int fb = blockIdx.x + 64 * (blockIdx.y + 4 * blockIdx.z);
    if (fb < 768) {            // 768*256 = 196608 = 3 x 256x256 weights
        int i = fb * 256 + threadIdx.x;
        int sel = i >> 16, off = i & 65535;
        const float* s = sel == 0 ? tw : (sel == 1 ? pw : cw);
        unsigned short* d = sel == 0 ? Wbt : (sel == 1 ? Wbp : Wbc);
        d[off] = f2b(s[off]);
    }
    int n = blockIdx.z, c0 = blockIdx.y * 64, p0 = blockIdx.x * 64;
    int t = threadIdx.x;
    int pl = t & 63, rg = t >> 6;
    const float* xp = x + ((size_t)n * CC + c0) * HW + p0;
    #pragma unroll
    for (int i = 0; i < 16; i++) {
        int cl = rg * 16 + i;
        float v = xp[(size_t)cl * HW + pl];
        T[cl][pl] = v;
        gb[((size_t)n * CC + c0 + cl) * HW + p0 + pl] = f2b(v);
    }
    __syncthreads();
    int cl = t & 63, pg = t >> 6;
    unsigned short* xt = XT + ((size_t)n * HW + p0) * CC + c0;
    #pragma unroll
    for (int i = 0; i < 16; i++) {
        int plw = pg * 16 + i;
        xt[(size_t)plw * CC + cl] = f2b(T[cl][plw]);
    }
}

// ---- kernel 2: projection GEMM  outT[p][co] = sum_ci XT[p][ci]*W[co][ci] + b[co] ----
__global__ __launch_bounds__(256) void k_proj(const unsigned short* __restrict__ XT,
                                              const unsigned short* __restrict__ Wt,
                                              const unsigned short* __restrict__ Wp,
                                              const float* __restrict__ bt,
                                              const float* __restrict__ bp,
                                              unsigned short* __restrict__ outT_t,
                                              unsigned short* __restrict__ outT_p) {
    const unsigned short* W; const float* b; unsigned short* outT;
    if (blockIdx.y == 0) { W = Wt; b = bt; outT = outT_t; }
    else                 { W = Wp; b = bp; outT = outT_p; }
    int w = threadIdx.x >> 6, lane = threadIdx.x & 63;
    int nidx = lane & 15, quad = lane >> 4;
    size_t row0 = (size_t)blockIdx.x * 64 + w * 16;
    float4_t acc[16];
    #pragma unroll
    for (int i = 0; i < 16; i++) acc[i] = (float4_t)(0.f);
    const unsigned short* arow = XT + (row0 + nidx) * CC + quad * 8;
    for (int ks = 0; ks < 8; ks++) {
        short8 a = *(const short8*)(arow + ks * 32);
        #pragma unroll
        for (int cb = 0; cb < 16; cb++) {
            short8 bb = *(const short8*)(W + (size_t)(cb * 16 + nidx) * CC + ks * 32 + quad * 8);
            acc[cb] = __builtin_amdgcn_mfma_f32_16x16x32_bf16(a, bb, acc[cb], 0, 0, 0);
        }
    }
    #pragma unroll
    for (int cb = 0; cb < 16; cb++) {
        int co = cb * 16 + nidx;
        float bias = b[co];
        #pragma unroll
        for (int r = 0; r < 4; r++) {
            size_t prow = row0 + quad * 4 + r;
            outT[prow * CC + co] = f2b(acc[cb][r] + bias);
        }
    }
}

// ---- kernel 3: flash attention, key-split across 2 blocks per q-tile.
// Grid 512: block handles 64 q x 2048 keys (32 tiles of 64). Writes
// unnormalized fp32 partial O [h][q_global][ch] + partial l [h][q_global].
// QK^T role-swapped (A=K, B=theta -> S^T), P relayed fragment-major via LDS,
// PV: A=V (wave's 64 ch), B=P. 2 blocks/CU overlap each other's stalls.
__global__ __launch_bounds__(256, 2)
void k_attn(const unsigned short* __restrict__ thetaT,
            const unsigned short* __restrict__ phiT,
            const unsigned short* __restrict__ gb,
            float* __restrict__ Ow, float* __restrict__ lw) {
    __shared__ __align__(16) ushort Pbuf[2][8][64][8];   // [buf][frag(qt*2+kst)][lane][8] = 16 KB
    __shared__ float Lbuf[4][64];

    const int tid = threadIdx.x;
    const int w = tid >> 6, lane = tid & 63;
    const int nidx = lane & 15, quad = lane >> 4;
    const int nb = (blockIdx.x & 7) >> 1;                // batch -> XCD pair
    const int tile = ((((blockIdx.x >> 3) & 31) << 1) | (blockIdx.x & 1));
    const int h = (blockIdx.x >> 8) & 1;                 // key half
    const int p0 = tile * 64;
    const size_t seq0 = (size_t)nb * HW;
    const ushort* Kg = phiT + seq0 * CC;                 // [4096][256]
    const ushort* Vg = gb + (size_t)nb * CC * HW;        // [256][4096]
    const int k00 = h * 2048;                            // this block's key range base

    // persistent theta B-frags: th[qt][kb] : B[ch=quad*8+j][q=qt*16+nidx]
    short8 th[4][8];
    #pragma unroll
    for (int qt = 0; qt < 4; qt++) {
        const ushort* qrow = thetaT + (seq0 + p0 + qt * 16 + nidx) * CC + quad * 8;
        #pragma unroll
        for (int kb = 0; kb < 8; kb++) th[qt][kb] = *(const short8*)(qrow + kb * 32);
    }

    float4_t o[4][4];
    #pragma unroll
    for (int i = 0; i < 4; i++)
        #pragma unroll
        for (int j = 0; j < 4; j++) o[i][j] = (float4_t)(0.f);
    float lrow[4] = {0.f, 0.f, 0.f, 0.f};

    const ushort* kbase = Kg + (size_t)(k00 + w * 16 + nidx) * CC + quad * 8;
    const float SC = 0.0625f * 1.44269504088896f;        // /sqrt(256) * log2(e)

    auto loadK = [&](short8 (&kr)[8], int t) {
        const ushort* p = kbase + (size_t)t * 64 * CC;
        #pragma unroll
        for (int kb = 0; kb < 8; kb++) kr[kb] = *(const short8*)(p + kb * 32);
    };
    auto loadV = [&](short8 (&vr)[8], int t) {
        #pragma unroll
        for (int ct = 0; ct < 4; ct++)
            #pragma unroll
            for (int kst = 0; kst < 2; kst++)
                vr[ct * 2 + kst] = *(const short8*)(Vg + (size_t)(w * 64 + ct * 16 + nidx) * HW
                                                    + k00 + t * 64 + kst * 32 + quad * 8);
    };
    // P write target: frag (qt, kst=w>>1), cell lane = ((w&1)*2+(quad>>1))*16+nidx,
    // ushort offset (quad&1)*4
    const int pfrag_k = w >> 1;
    const int pcell = ((w & 1) * 2 + (quad >> 1)) * 16 + nidx;
    const int poff = (quad & 1) * 4;

    auto body = [&](const short8 (&kr)[8], const short8 (&vr)[8], int t) {
        const int buf = t & 1;
        // ---- QK^T: S^T[16 keys of wave][64 q], 4 independent acc chains ----
        float4_t s0 = (float4_t)(0.f), s1 = (float4_t)(0.f);
        float4_t s2 = (float4_t)(0.f), s3 = (float4_t)(0.f);
        #pragma unroll
        for (int kb = 0; kb < 8; kb++) {
            s0 = __builtin_amdgcn_mfma_f32_16x16x32_bf16(kr[kb], th[0][kb], s0, 0, 0, 0);
            s1 = __builtin_amdgcn_mfma_f32_16x16x32_bf16(kr[kb], th[1][kb], s1, 0, 0, 0);
            s2 = __builtin_amdgcn_mfma_f32_16x16x32_bf16(kr[kb], th[2][kb], s2, 0, 0, 0);
            s3 = __builtin_amdgcn_mfma_f32_16x16x32_bf16(kr[kb], th[3][kb], s3, 0, 0, 0);
        }
        // ---- exp, row-sum partials, pack to P relay (fragment-major) ----
        {
            float e0 = exp2f(s0[0] * SC), e1 = exp2f(s0[1] * SC);
            float e2 = exp2f(s0[2] * SC), e3 = exp2f(s0[3] * SC);
            lrow[0] += e0 + e1 + e2 + e3;
            short4_t pk = { (short)f2b(e0), (short)f2b(e1), (short)f2b(e2), (short)f2b(e3) };
            *(short4_t*)(&Pbuf[buf][0 * 2 + pfrag_k][pcell][poff]) = pk;
        }
        {
            float e0 = exp2f(s1[0] * SC), e1 = exp2f(s1[1] * SC);
            float e2 = exp2f(s1[2] * SC), e3 = exp2f(s1[3] * SC);
            lrow[1] += e0 + e1 + e2 + e3;
            short4_t pk = { (short)f2b(e0), (short)f2b(e1), (short)f2b(e2), (short)f2b(e3) };
            *(short4_t*)(&Pbuf[buf][1 * 2 + pfrag_k][pcell][poff]) = pk;
        }
        {
            float e0 = exp2f(s2[0] * SC), e1 = exp2f(s2[1] * SC);
            float e2 = exp2f(s2[2] * SC), e3 = exp2f(s2[3] * SC);
            lrow[2] += e0 + e1 + e2 + e3;
            short4_t pk = { (short)f2b(e0), (short)f2b(e1), (short)f2b(e2), (short)f2b(e3) };
            *(short4_t*)(&Pbuf[buf][2 * 2 + pfrag_k][pcell][poff]) = pk;
        }
        {
            float e0 = exp2f(s3[0] * SC), e1 = exp2f(s3[1] * SC);
            float e2 = exp2f(s3[2] * SC), e3 = exp2f(s3[3] * SC);
            lrow[3] += e0 + e1 + e2 + e3;
            short4_t pk = { (short)f2b(e0), (short)f2b(e1), (short)f2b(e2), (short)f2b(e3) };
            *(short4_t*)(&Pbuf[buf][3 * 2 + pfrag_k][pcell][poff]) = pk;
        }
        __syncthreads();                                  // P(t) complete
        // ---- PV: o[ch 64 of wave][q 64] += V * P ----
        short8 pf[8];
        #pragma unroll
        for (int f = 0; f < 8; f++)
            pf[f] = *(const short8*)(&Pbuf[buf][f][lane][0]);
        #pragma unroll
        for (int ct = 0; ct < 4; ct++)
            #pragma unroll
            for (int qt = 0; qt < 4; qt++)
                #pragma unroll
                for (int kst = 0; kst < 2; kst++)
                    o[ct][qt] = __builtin_amdgcn_mfma_f32_16x16x32_bf16(
                        vr[ct * 2 + kst], pf[qt * 2 + kst], o[ct][qt], 0, 0, 0);
    };

    short8 kA[8], kB[8], vA[8], vB[8];
    loadK(kA, 0); loadV(vA, 0);
    #pragma unroll 1
    for (int tt = 0; tt < 16; tt++) {
        const int t0 = tt * 2;
        const int tn1 = t0 + 1;
        const int tn2 = t0 + 2 < 32 ? t0 + 2 : 31;
        loadK(kB, tn1); loadV(vB, tn1);                   // prefetch odd tile
        body(kA, vA, t0);
        loadK(kA, tn2); loadV(vA, tn2);                   // prefetch next even tile
        body(kB, vB, tn1);
    }

    // ---- epilogue: reduce partial l across quads + waves, store partials ----
    #pragma unroll
    for (int qt = 0; qt < 4; qt++) {
        float v = lrow[qt];
        v += __shfl_xor(v, 16);
        v += __shfl_xor(v, 32);
        if (quad == 0) Lbuf[w][qt * 16 + nidx] = v;
    }
    __syncthreads();
    if (tid < 64)
        lw[(size_t)h * SEQ + seq0 + p0 + tid] =
            Lbuf[0][tid] + Lbuf[1][tid] + Lbuf[2][tid] + Lbuf[3][tid];
    // lane holds O[ch = w*64+ct*16+quad*4+r][q = qt*16+nidx]; store rows=q, cols=ch
    float* Op = Ow + ((size_t)h * SEQ + seq0 + p0) * CC;
    #pragma unroll
    for (int ct = 0; ct < 4; ct++)
        #pragma unroll
        for (int qt = 0; qt < 4; qt++)
            *(float4_t*)(Op + (size_t)(qt * 16 + nidx) * CC + w * 64 + ct * 16 + quad * 4) = o[ct][qt];
}

// ---- kernel 3b: combine key-halves: fT[q][ch] = (O0+O1)/(l0+l1) as bf16 ----
__global__ __launch_bounds__(256) void k_reduce(const float* __restrict__ Ow,
                                                const float* __restrict__ lw,
                                                unsigned short* __restrict__ fT) {
    const float4_t* O0 = (const float4_t*)Ow;
    const float4_t* O1 = (const float4_t*)(Ow + SEQ * CC);
    int i0 = blockIdx.x * 256 + threadIdx.x;             // grid 1024 x 4 iters
    #pragma unroll
    for (int j = 0; j < 4; j++) {
        int idx = j * 262144 + i0;                       // float4 index, SEQ*CC/4 total
        int row = idx >> 6;                              // 64 float4 per 256-ch row
        float li = 1.0f / (lw[row] + lw[SEQ + row]);
        float4_t a = O0[idx];
        float4_t b = O1[idx];
        short4_t pk;
        #pragma unroll
        for (int r = 0; r < 4; r++) pk[r] = (short)f2b((a[r] + b[r]) * li);
        *(short4_t*)(fT + (size_t)idx * 4) = pk;
    }
}

// ---- kernel 4: out[n][co][p] = x + b[co] + sum_k W[co][k]*fT[p][k] ----
__global__ __launch_bounds__(256) void k_final(const unsigned short* __restrict__ Wc,
                                               const float* __restrict__ bc,
                                               const unsigned short* __restrict__ fT,
                                               const float* __restrict__ x,
                                               float* __restrict__ out) {
    int w = threadIdx.x >> 6, lane = threadIdx.x & 63;
    int nidx = lane & 15, quad = lane >> 4;
    int n = blockIdx.z;
    int co0 = blockIdx.y * 64 + w * 16;
    int p0 = blockIdx.x * 64;
    float4_t acc[4];
    #pragma unroll
    for (int i = 0; i < 4; i++) acc[i] = (float4_t)(0.f);
    const unsigned short* arow = Wc + (size_t)(co0 + nidx) * CC + quad * 8;
    const unsigned short* brow = fT + ((size_t)n * HW + p0 + nidx) * CC + quad * 8;
    for (int ks = 0; ks < 8; ks++) {
        short8 a = *(const short8*)(arow + ks * 32);
        #pragma unroll
        for (int pb = 0; pb < 4; pb++) {
            short8 bb = *(const short8*)(brow + (size_t)pb * 16 * CC + ks * 32);
            acc[pb] = __builtin_amdgcn_mfma_f32_16x16x32_bf16(a, bb, acc[pb], 0, 0, 0);
        }
    }
    #pragma unroll
    for (int pb = 0; pb < 4; pb++) {
        #pragma unroll
        for (int r = 0; r < 4; r++) {
            int co = co0 + quad * 4 + r;
            size_t idx = ((size_t)n * CC + co) * HW + p0 + pb * 16 + nidx;
            out[idx] = x[idx] + bc[co] + acc[pb][r];
        }
    }
}

extern "C" void kernel_launch(void* const* d_in, const int* in_sizes, int n_in,
                              void* d_out, int out_size, void* d_ws, size_t ws_size,
                              hipStream_t stream) {
    const float* x       = (const float*)d_in[0];
    const float* theta_w = (const float*)d_in[1];
    const float* theta_b = (const float*)d_in[2];
    const float* phi_w   = (const float*)d_in[3];
    const float* phi_b   = (const float*)d_in[4];
    const float* conv1_w = (const float*)d_in[5];
    const float* conv1_b = (const float*)d_in[6];
    float* out = (float*)d_out;

    unsigned short* XT  = (unsigned short*)d_ws;  // [SEQ][256] bf16
    unsigned short* gb  = XT  + SEQ * CC;         // [N][256][4096]
    unsigned short* thT = gb  + SEQ * CC;         // [SEQ][256]
    unsigned short* phT = thT + SEQ * CC;         // [SEQ][256]
    unsigned short* fT  = phT + SEQ * CC;         // [SEQ][256]
    unsigned short* Wbt = fT  + SEQ * CC;
    unsigned short* Wbp = Wbt + 65536;
    unsigned short* Wbc = Wbp + 65536;
    float* Ow = (float*)(Wbc + 65536);            // [2][SEQ][256] fp32 partial O
    float* lw = Ow + 2 * SEQ * CC;                // [2][SEQ] fp32 partial l

    k_prep<<<dim3(64, 4, 4), 256, 0, stream>>>(x, theta_w, phi_w, conv1_w, XT, gb, Wbt, Wbp, Wbc);
    k_proj<<<dim3(256, 2), 256, 0, stream>>>(XT, Wbt, Wbp, theta_b, phi_b, thT, phT);
    k_attn<<<dim3(512), 256, 0, stream>>>(thT, phT, gb, Ow, lw);
    k_reduce<<<dim3(1024), 256, 0, stream>>>(Ow, lw, fT);
    k_final<<<dim3(64, 4, 4), 256, 0, stream>>>(Wbc, conv1_b, fT, x, out);
}

// Round 6
// 386.966 us; speedup vs baseline: 1.5255x; 1.5255x over previous
//
#include <hip/hip_runtime.h>
#include <hip/hip_bf16.h>

typedef __attribute__((ext_vector_type(8))) short short8;
typedef __attribute__((ext_vector_type(4))) short short4_t;
typedef __attribute__((ext_vector_type(4))) float float4_t;
typedef unsigned short ushort;

#define HW 4096
#define CC 256
#define NBATCH 4
#define SEQ ((size_t)NBATCH * HW)

static __device__ __forceinline__ unsigned short f2b(float f) {
    union { float f; unsigned u; } v; v.f = f;
    unsigned r = v.u + 0x7FFF + ((v.u >> 16) & 1);   // RNE
    return (unsigned short)(r >> 16);
}

// ---- kernel 1: x[n][c][p] -> XT[n][p][c] (bf16) and gb[n][c][p] (bf16),
//      with fused fp32->bf16 weight conversion (first 768 flat blocks). ----
__global__ __launch_bounds__(256) void k_prep(const float* __restrict__ x,
                                              const float* __restrict__ tw,
                                              const float* __restrict__ pw,
                                              const float* __restrict__ cw,
                                              unsigned short* __restrict__ XT,
                                              unsigned short* __restrict__ gb,
                                              unsigned short* __restrict__ Wbt,
                                              unsigned short* __restrict__ Wbp,
                                              unsigned short* __restrict__ Wbc) {
    __shared__ float T[64][65];
    int fb = blockIdx.x + 64 * (blockIdx.y + 4 * blockIdx.z);
    if (fb < 768) {            // 768*256 = 196608 = 3 x 256x256 weights
        int i = fb * 256 + threadIdx.x;
        int sel = i >> 16, off = i & 65535;
        const float* s = sel == 0 ? tw : (sel == 1 ? pw : cw);
        unsigned short* d = sel == 0 ? Wbt : (sel == 1 ? Wbp : Wbc);
        d[off] = f2b(s[off]);
    }
    int n = blockIdx.z, c0 = blockIdx.y * 64, p0 = blockIdx.x * 64;
    int t = threadIdx.x;
    int pl = t & 63, rg = t >> 6;
    const float* xp = x + ((size_t)n * CC + c0) * HW + p0;
    #pragma unroll
    for (int i = 0; i < 16; i++) {
        int cl = rg * 16 + i;
        float v = xp[(size_t)cl * HW + pl];
        T[cl][pl] = v;
        gb[((size_t)n * CC + c0 + cl) * HW + p0 + pl] = f2b(v);
    }
    __syncthreads();
    int cl = t & 63, pg = t >> 6;
    unsigned short* xt = XT + ((size_t)n * HW + p0) * CC + c0;
    #pragma unroll
    for (int i = 0; i < 16; i++) {
        int plw = pg * 16 + i;
        xt[(size_t)plw * CC + cl] = f2b(T[cl][plw]);
    }
}

// ---- kernel 2: projection GEMM  outT[p][co] = sum_ci XT[p][ci]*W[co][ci] + b[co] ----
__global__ __launch_bounds__(256) void k_proj(const unsigned short* __restrict__ XT,
                                              const unsigned short* __restrict__ Wt,
                                              const unsigned short* __restrict__ Wp,
                                              const float* __restrict__ bt,
                                              const float* __restrict__ bp,
                                              unsigned short* __restrict__ outT_t,
                                              unsigned short* __restrict__ outT_p) {
    const unsigned short* W; const float* b; unsigned short* outT;
    if (blockIdx.y == 0) { W = Wt; b = bt; outT = outT_t; }
    else                 { W = Wp; b = bp; outT = outT_p; }
    int w = threadIdx.x >> 6, lane = threadIdx.x & 63;
    int nidx = lane & 15, quad = lane >> 4;
    size_t row0 = (size_t)blockIdx.x * 64 + w * 16;
    float4_t acc[16];
    #pragma unroll
    for (int i = 0; i < 16; i++) acc[i] = (float4_t)(0.f);
    const unsigned short* arow = XT + (row0 + nidx) * CC + quad * 8;
    for (int ks = 0; ks < 8; ks++) {
        short8 a = *(const short8*)(arow + ks * 32);
        #pragma unroll
        for (int cb = 0; cb < 16; cb++) {
            short8 bb = *(const short8*)(W + (size_t)(cb * 16 + nidx) * CC + ks * 32 + quad * 8);
            acc[cb] = __builtin_amdgcn_mfma_f32_16x16x32_bf16(a, bb, acc[cb], 0, 0, 0);
        }
    }
    #pragma unroll
    for (int cb = 0; cb < 16; cb++) {
        int co = cb * 16 + nidx;
        float bias = b[co];
        #pragma unroll
        for (int r = 0; r < 4; r++) {
            size_t prow = row0 + quad * 4 + r;
            outT[prow * CC + co] = f2b(acc[cb][r] + bias);
        }
    }
}

// ---- kernel 3: flash attention, key-split across 2 blocks per q-tile.
// Grid 512: block handles 64 q x 2048 keys (32 tiles of 64). Writes
// unnormalized fp32 partial O + partial l. QK^T role-swapped (A=K, B=theta),
// P relayed fragment-major via LDS, PV: A=V, B=P.
// Round-6: SINGLE-buffered K/V prefetch regs (WAR-safe issue order) to cut
// ~64 VGPR so 2 waves/SIMD fit; amdgpu_waves_per_eu(2) (NOT launch_bounds
// 2nd arg, which capped VGPR=128 and spilled 1.4 GB in round 5).
__global__ __launch_bounds__(256) __attribute__((amdgpu_waves_per_eu(2)))
void k_attn(const unsigned short* __restrict__ thetaT,
            const unsigned short* __restrict__ phiT,
            const unsigned short* __restrict__ gb,
            float* __restrict__ Ow, float* __restrict__ lw) {
    __shared__ __align__(16) ushort Pbuf[2][8][64][8];   // [buf][frag(qt*2+kst)][lane][8] = 16 KB
    __shared__ float Lbuf[4][64];

    const int tid = threadIdx.x;
    const int w = tid >> 6, lane = tid & 63;
    const int nidx = lane & 15, quad = lane >> 4;
    const int nb = (blockIdx.x & 7) >> 1;                // batch -> XCD pair
    const int tile = ((((blockIdx.x >> 3) & 31) << 1) | (blockIdx.x & 1));
    const int h = (blockIdx.x >> 8) & 1;                 // key half
    const int p0 = tile * 64;
    const size_t seq0 = (size_t)nb * HW;
    const ushort* Kg = phiT + seq0 * CC;                 // [4096][256]
    const ushort* Vg = gb + (size_t)nb * CC * HW;        // [256][4096]
    const int k00 = h * 2048;                            // this block's key range base

    // persistent theta B-frags: th[qt][kb] : B[ch=quad*8+j][q=qt*16+nidx]
    short8 th[4][8];
    #pragma unroll
    for (int qt = 0; qt < 4; qt++) {
        const ushort* qrow = thetaT + (seq0 + p0 + qt * 16 + nidx) * CC + quad * 8;
        #pragma unroll
        for (int kb = 0; kb < 8; kb++) th[qt][kb] = *(const short8*)(qrow + kb * 32);
    }

    float4_t o[4][4];
    #pragma unroll
    for (int i = 0; i < 4; i++)
        #pragma unroll
        for (int j = 0; j < 4; j++) o[i][j] = (float4_t)(0.f);
    float lrow[4] = {0.f, 0.f, 0.f, 0.f};

    const ushort* kbase = Kg + (size_t)(k00 + w * 16 + nidx) * CC + quad * 8;
    const float SC = 0.0625f * 1.44269504088896f;        // /sqrt(256) * log2(e)

    auto loadK = [&](short8 (&kr)[8], int t) {
        const ushort* p = kbase + (size_t)t * 64 * CC;
        #pragma unroll
        for (int kb = 0; kb < 8; kb++) kr[kb] = *(const short8*)(p + kb * 32);
    };
    auto loadV = [&](short8 (&vr)[8], int t) {
        #pragma unroll
        for (int ct = 0; ct < 4; ct++)
            #pragma unroll
            for (int kst = 0; kst < 2; kst++)
                vr[ct * 2 + kst] = *(const short8*)(Vg + (size_t)(w * 64 + ct * 16 + nidx) * HW
                                                    + k00 + t * 64 + kst * 32 + quad * 8);
    };
    // P write target: frag (qt, kst=w>>1), cell lane = ((w&1)*2+(quad>>1))*16+nidx,
    // ushort offset (quad&1)*4
    const int pfrag_k = w >> 1;
    const int pcell = ((w & 1) * 2 + (quad >> 1)) * 16 + nidx;
    const int poff = (quad & 1) * 4;

    short8 kr[8], vr[8];
    loadK(kr, 0); loadV(vr, 0);

    #pragma unroll 1
    for (int t = 0; t < 32; t++) {
        const int buf = t & 1;
        const int tn = (t + 1 < 32) ? t + 1 : 31;
        // ---- QK^T: S^T[16 keys of wave][64 q], 4 independent acc chains ----
        float4_t s0 = (float4_t)(0.f), s1 = (float4_t)(0.f);
        float4_t s2 = (float4_t)(0.f), s3 = (float4_t)(0.f);
        #pragma unroll
        for (int kb = 0; kb < 8; kb++) {
            s0 = __builtin_amdgcn_mfma_f32_16x16x32_bf16(kr[kb], th[0][kb], s0, 0, 0, 0);
            s1 = __builtin_amdgcn_mfma_f32_16x16x32_bf16(kr[kb], th[1][kb], s1, 0, 0, 0);
            s2 = __builtin_amdgcn_mfma_f32_16x16x32_bf16(kr[kb], th[2][kb], s2, 0, 0, 0);
            s3 = __builtin_amdgcn_mfma_f32_16x16x32_bf16(kr[kb], th[3][kb], s3, 0, 0, 0);
        }
        loadK(kr, tn);       // WAR-safe: QK(t) already consumed kr; lands during exp+PV
        // ---- exp, row-sum partials, pack to P relay (fragment-major) ----
        {
            float e0 = exp2f(s0[0] * SC), e1 = exp2f(s0[1] * SC);
            float e2 = exp2f(s0[2] * SC), e3 = exp2f(s0[3] * SC);
            lrow[0] += e0 + e1 + e2 + e3;
            short4_t pk = { (short)f2b(e0), (short)f2b(e1), (short)f2b(e2), (short)f2b(e3) };
            *(short4_t*)(&Pbuf[buf][0 * 2 + pfrag_k][pcell][poff]) = pk;
        }
        {
            float e0 = exp2f(s1[0] * SC), e1 = exp2f(s1[1] * SC);
            float e2 = exp2f(s1[2] * SC), e3 = exp2f(s1[3] * SC);
            lrow[1] += e0 + e1 + e2 + e3;
            short4_t pk = { (short)f2b(e0), (short)f2b(e1), (short)f2b(e2), (short)f2b(e3) };
            *(short4_t*)(&Pbuf[buf][1 * 2 + pfrag_k][pcell][poff]) = pk;
        }
        {
            float e0 = exp2f(s2[0] * SC), e1 = exp2f(s2[1] * SC);
            float e2 = exp2f(s2[2] * SC), e3 = exp2f(s2[3] * SC);
            lrow[2] += e0 + e1 + e2 + e3;
            short4_t pk = { (short)f2b(e0), (short)f2b(e1), (short)f2b(e2), (short)f2b(e3) };
            *(short4_t*)(&Pbuf[buf][2 * 2 + pfrag_k][pcell][poff]) = pk;
        }
        {
            float e0 = exp2f(s3[0] * SC), e1 = exp2f(s3[1] * SC);
            float e2 = exp2f(s3[2] * SC), e3 = exp2f(s3[3] * SC);
            lrow[3] += e0 + e1 + e2 + e3;
            short4_t pk = { (short)f2b(e0), (short)f2b(e1), (short)f2b(e2), (short)f2b(e3) };
            *(short4_t*)(&Pbuf[buf][3 * 2 + pfrag_k][pcell][poff]) = pk;
        }
        __syncthreads();                                  // P(t) complete
        // ---- PV: o[ch 64 of wave][q 64] += V * P ----
        short8 pf[8];
        #pragma unroll
        for (int f = 0; f < 8; f++)
            pf[f] = *(const short8*)(&Pbuf[buf][f][lane][0]);
        #pragma unroll
        for (int ct = 0; ct < 4; ct++)
            #pragma unroll
            for (int qt = 0; qt < 4; qt++)
                #pragma unroll
                for (int kst = 0; kst < 2; kst++)
                    o[ct][qt] = __builtin_amdgcn_mfma_f32_16x16x32_bf16(
                        vr[ct * 2 + kst], pf[qt * 2 + kst], o[ct][qt], 0, 0, 0);
        loadV(vr, tn);       // WAR-safe: PV(t) consumed vr; lands during next QK+exp
    }

    // ---- epilogue: reduce partial l across quads + waves, store partials ----
    #pragma unroll
    for (int qt = 0; qt < 4; qt++) {
        float v = lrow[qt];
        v += __shfl_xor(v, 16);
        v += __shfl_xor(v, 32);
        if (quad == 0) Lbuf[w][qt * 16 + nidx] = v;
    }
    __syncthreads();
    if (tid < 64)
        lw[(size_t)h * SEQ + seq0 + p0 + tid] =
            Lbuf[0][tid] + Lbuf[1][tid] + Lbuf[2][tid] + Lbuf[3][tid];
    // lane holds O[ch = w*64+ct*16+quad*4+r][q = qt*16+nidx]; store rows=q, cols=ch
    float* Op = Ow + ((size_t)h * SEQ + seq0 + p0) * CC;
    #pragma unroll
    for (int ct = 0; ct < 4; ct++)
        #pragma unroll
        for (int qt = 0; qt < 4; qt++)
            *(float4_t*)(Op + (size_t)(qt * 16 + nidx) * CC + w * 64 + ct * 16 + quad * 4) = o[ct][qt];
}

// ---- kernel 3b: combine key-halves: fT[q][ch] = (O0+O1)/(l0+l1) as bf16 ----
__global__ __launch_bounds__(256) void k_reduce(const float* __restrict__ Ow,
                                                const float* __restrict__ lw,
                                                unsigned short* __restrict__ fT) {
    const float4_t* O0 = (const float4_t*)Ow;
    const float4_t* O1 = (const float4_t*)(Ow + SEQ * CC);
    int i0 = blockIdx.x * 256 + threadIdx.x;             // grid 1024 x 4 iters
    #pragma unroll
    for (int j = 0; j < 4; j++) {
        int idx = j * 262144 + i0;                       // float4 index, SEQ*CC/4 total
        int row = idx >> 6;                              // 64 float4 per 256-ch row
        float li = 1.0f / (lw[row] + lw[SEQ + row]);
        float4_t a = O0[idx];
        float4_t b = O1[idx];
        short4_t pk;
        #pragma unroll
        for (int r = 0; r < 4; r++) pk[r] = (short)f2b((a[r] + b[r]) * li);
        *(short4_t*)(fT + (size_t)idx * 4) = pk;
    }
}

// ---- kernel 4: out[n][co][p] = x + b[co] + sum_k W[co][k]*fT[p][k] ----
__global__ __launch_bounds__(256) void k_final(const unsigned short* __restrict__ Wc,
                                               const float* __restrict__ bc,
                                               const unsigned short* __restrict__ fT,
                                               const float* __restrict__ x,
                                               float* __restrict__ out) {
    int w = threadIdx.x >> 6, lane = threadIdx.x & 63;
    int nidx = lane & 15, quad = lane >> 4;
    int n = blockIdx.z;
    int co0 = blockIdx.y * 64 + w * 16;
    int p0 = blockIdx.x * 64;
    float4_t acc[4];
    #pragma unroll
    for (int i = 0; i < 4; i++) acc[i] = (float4_t)(0.f);
    const unsigned short* arow = Wc + (size_t)(co0 + nidx) * CC + quad * 8;
    const unsigned short* brow = fT + ((size_t)n * HW + p0 + nidx) * CC + quad * 8;
    for (int ks = 0; ks < 8; ks++) {
        short8 a = *(const short8*)(arow + ks * 32);
        #pragma unroll
        for (int pb = 0; pb < 4; pb++) {
            short8 bb = *(const short8*)(brow + (size_t)pb * 16 * CC + ks * 32);
            acc[pb] = __builtin_amdgcn_mfma_f32_16x16x32_bf16(a, bb, acc[pb], 0, 0, 0);
        }
    }
    #pragma unroll
    for (int pb = 0; pb < 4; pb++) {
        #pragma unroll
        for (int r = 0; r < 4; r++) {
            int co = co0 + quad * 4 + r;
            size_t idx = ((size_t)n * CC + co) * HW + p0 + pb * 16 + nidx;
            out[idx] = x[idx] + bc[co] + acc[pb][r];
        }
    }
}

extern "C" void kernel_launch(void* const* d_in, const int* in_sizes, int n_in,
                              void* d_out, int out_size, void* d_ws, size_t ws_size,
                              hipStream_t stream) {
    const float* x       = (const float*)d_in[0];
    const float* theta_w = (const float*)d_in[1];
    const float* theta_b = (const float*)d_in[2];
    const float* phi_w   = (const float*)d_in[3];
    const float* phi_b   = (const float*)d_in[4];
    const float* conv1_w = (const float*)d_in[5];
    const float* conv1_b = (const float*)d_in[6];
    float* out = (float*)d_out;

    unsigned short* XT  = (unsigned short*)d_ws;  // [SEQ][256] bf16
    unsigned short* gb  = XT  + SEQ * CC;         // [N][256][4096]
    unsigned short* thT = gb  + SEQ * CC;         // [SEQ][256]
    unsigned short* phT = thT + SEQ * CC;         // [SEQ][256]
    unsigned short* fT  = phT + SEQ * CC;         // [SEQ][256]
    unsigned short* Wbt = fT  + SEQ * CC;
    unsigned short* Wbp = Wbt + 65536;
    unsigned short* Wbc = Wbp + 65536;
    float* Ow = (float*)(Wbc + 65536);            // [2][SEQ][256] fp32 partial O
    float* lw = Ow + 2 * SEQ * CC;                // [2][SEQ] fp32 partial l

    k_prep<<<dim3(64, 4, 4), 256, 0, stream>>>(x, theta_w, phi_w, conv1_w, XT, gb, Wbt, Wbp, Wbc);
    k_proj<<<dim3(256, 2), 256, 0, stream>>>(XT, Wbt, Wbp, theta_b, phi_b, thT, phT);
    k_attn<<<dim3(512), 256, 0, stream>>>(thT, phT, gb, Ow, lw);
    k_reduce<<<dim3(1024), 256, 0, stream>>>(Ow, lw, fT);
    k_final<<<dim3(64, 4, 4), 256, 0, stream>>>(Wbc, conv1_b, fT, x, out);
}

// Round 7
// 272.736 us; speedup vs baseline: 2.1644x; 1.4188x over previous
//
#include <hip/hip_runtime.h>
#include <hip/hip_bf16.h>

typedef __attribute__((ext_vector_type(8))) short short8;
typedef __attribute__((ext_vector_type(4))) short short4_t;
typedef __attribute__((ext_vector_type(4))) float float4_t;
typedef unsigned short ushort;

#define HW 4096
#define CC 256
#define NBATCH 4
#define SEQ ((size_t)NBATCH * HW)

static __device__ __forceinline__ unsigned short f2b(float f) {
    union { float f; unsigned u; } v; v.f = f;
    unsigned r = v.u + 0x7FFF + ((v.u >> 16) & 1);   // RNE
    return (unsigned short)(r >> 16);
}

// ---- kernel 1: x[n][c][p] -> XT[n][p][c] (bf16) and gb[n][c][p] (bf16),
//      with fused fp32->bf16 weight conversion (first 768 flat blocks). ----
__global__ __launch_bounds__(256) void k_prep(const float* __restrict__ x,
                                              const float* __restrict__ tw,
                                              const float* __restrict__ pw,
                                              const float* __restrict__ cw,
                                              unsigned short* __restrict__ XT,
                                              unsigned short* __restrict__ gb,
                                              unsigned short* __restrict__ Wbt,
                                              unsigned short* __restrict__ Wbp,
                                              unsigned short* __restrict__ Wbc) {
    __shared__ float T[64][65];
    int fb = blockIdx.x + 64 * (blockIdx.y + 4 * blockIdx.z);
    if (fb < 768) {            // 768*256 = 196608 = 3 x 256x256 weights
        int i = fb * 256 + threadIdx.x;
        int sel = i >> 16, off = i & 65535;
        const float* s = sel == 0 ? tw : (sel == 1 ? pw : cw);
        unsigned short* d = sel == 0 ? Wbt : (sel == 1 ? Wbp : Wbc);
        d[off] = f2b(s[off]);
    }
    int n = blockIdx.z, c0 = blockIdx.y * 64, p0 = blockIdx.x * 64;
    int t = threadIdx.x;
    int pl = t & 63, rg = t >> 6;
    const float* xp = x + ((size_t)n * CC + c0) * HW + p0;
    #pragma unroll
    for (int i = 0; i < 16; i++) {
        int cl = rg * 16 + i;
        float v = xp[(size_t)cl * HW + pl];
        T[cl][pl] = v;
        gb[((size_t)n * CC + c0 + cl) * HW + p0 + pl] = f2b(v);
    }
    __syncthreads();
    int cl = t & 63, pg = t >> 6;
    unsigned short* xt = XT + ((size_t)n * HW + p0) * CC + c0;
    #pragma unroll
    for (int i = 0; i < 16; i++) {
        int plw = pg * 16 + i;
        xt[(size_t)plw * CC + cl] = f2b(T[cl][plw]);
    }
}

// ---- kernel 2: projection GEMM  outT[p][co] = sum_ci XT[p][ci]*W[co][ci] + b[co] ----
__global__ __launch_bounds__(256) void k_proj(const unsigned short* __restrict__ XT,
                                              const unsigned short* __restrict__ Wt,
                                              const unsigned short* __restrict__ Wp,
                                              const float* __restrict__ bt,
                                              const float* __restrict__ bp,
                                              unsigned short* __restrict__ outT_t,
                                              unsigned short* __restrict__ outT_p) {
    const unsigned short* W; const float* b; unsigned short* outT;
    if (blockIdx.y == 0) { W = Wt; b = bt; outT = outT_t; }
    else                 { W = Wp; b = bp; outT = outT_p; }
    int w = threadIdx.x >> 6, lane = threadIdx.x & 63;
    int nidx = lane & 15, quad = lane >> 4;
    size_t row0 = (size_t)blockIdx.x * 64 + w * 16;
    float4_t acc[16];
    #pragma unroll
    for (int i = 0; i < 16; i++) acc[i] = (float4_t)(0.f);
    const unsigned short* arow = XT + (row0 + nidx) * CC + quad * 8;
    for (int ks = 0; ks < 8; ks++) {
        short8 a = *(const short8*)(arow + ks * 32);
        #pragma unroll
        for (int cb = 0; cb < 16; cb++) {
            short8 bb = *(const short8*)(W + (size_t)(cb * 16 + nidx) * CC + ks * 32 + quad * 8);
            acc[cb] = __builtin_amdgcn_mfma_f32_16x16x32_bf16(a, bb, acc[cb], 0, 0, 0);
        }
    }
    #pragma unroll
    for (int cb = 0; cb < 16; cb++) {
        int co = cb * 16 + nidx;
        float bias = b[co];
        #pragma unroll
        for (int r = 0; r < 4; r++) {
            size_t prow = row0 + quad * 4 + r;
            outT[prow * CC + co] = f2b(acc[cb][r] + bias);
        }
    }
}

// ---- kernel 3: flash attention, key-split across 2 blocks per q-tile.
// Grid 512: block handles 64 q x 2048 keys (32 tiles of 64). Writes
// unnormalized fp32 partial O + partial l. QK^T role-swapped (A=K, B=theta),
// P relayed fragment-major via LDS, PV: A=V, B=P.
// Round-7: NO occupancy attribute. m69: waves/SIMD halve at vgpr={64,128,256},
// so the natural ~170-210 VGPR allocation already gives 2 waves/SIMD
// (= 2 blocks/CU at grid 512). Rounds 5/6 proved any forced cap (128) makes
// the compiler spill (r5: 1.4 GB scratch) or rematerialize (r6: 87 MB fetch).
__global__ __launch_bounds__(256)
void k_attn(const unsigned short* __restrict__ thetaT,
            const unsigned short* __restrict__ phiT,
            const unsigned short* __restrict__ gb,
            float* __restrict__ Ow, float* __restrict__ lw) {
    __shared__ __align__(16) ushort Pbuf[2][8][64][8];   // [buf][frag(qt*2+kst)][lane][8] = 16 KB
    __shared__ float Lbuf[4][64];

    const int tid = threadIdx.x;
    const int w = tid >> 6, lane = tid & 63;
    const int nidx = lane & 15, quad = lane >> 4;
    const int nb = (blockIdx.x & 7) >> 1;                // batch -> XCD pair
    const int tile = ((((blockIdx.x >> 3) & 31) << 1) | (blockIdx.x & 1));
    const int h = (blockIdx.x >> 8) & 1;                 // key half
    const int p0 = tile * 64;
    const size_t seq0 = (size_t)nb * HW;
    const ushort* Kg = phiT + seq0 * CC;                 // [4096][256]
    const ushort* Vg = gb + (size_t)nb * CC * HW;        // [256][4096]
    const int k00 = h * 2048;                            // this block's key range base

    // persistent theta B-frags: th[qt][kb] : B[ch=quad*8+j][q=qt*16+nidx]
    short8 th[4][8];
    #pragma unroll
    for (int qt = 0; qt < 4; qt++) {
        const ushort* qrow = thetaT + (seq0 + p0 + qt * 16 + nidx) * CC + quad * 8;
        #pragma unroll
        for (int kb = 0; kb < 8; kb++) th[qt][kb] = *(const short8*)(qrow + kb * 32);
    }

    float4_t o[4][4];
    #pragma unroll
    for (int i = 0; i < 4; i++)
        #pragma unroll
        for (int j = 0; j < 4; j++) o[i][j] = (float4_t)(0.f);
    float lrow[4] = {0.f, 0.f, 0.f, 0.f};

    const ushort* kbase = Kg + (size_t)(k00 + w * 16 + nidx) * CC + quad * 8;
    const float SC = 0.0625f * 1.44269504088896f;        // /sqrt(256) * log2(e)

    auto loadK = [&](short8 (&kr)[8], int t) {
        const ushort* p = kbase + (size_t)t * 64 * CC;
        #pragma unroll
        for (int kb = 0; kb < 8; kb++) kr[kb] = *(const short8*)(p + kb * 32);
    };
    auto loadV = [&](short8 (&vr)[8], int t) {
        #pragma unroll
        for (int ct = 0; ct < 4; ct++)
            #pragma unroll
            for (int kst = 0; kst < 2; kst++)
                vr[ct * 2 + kst] = *(const short8*)(Vg + (size_t)(w * 64 + ct * 16 + nidx) * HW
                                                    + k00 + t * 64 + kst * 32 + quad * 8);
    };
    // P write target: frag (qt, kst=w>>1), cell lane = ((w&1)*2+(quad>>1))*16+nidx,
    // ushort offset (quad&1)*4
    const int pfrag_k = w >> 1;
    const int pcell = ((w & 1) * 2 + (quad >> 1)) * 16 + nidx;
    const int poff = (quad & 1) * 4;

    short8 kr[8], vr[8];
    loadK(kr, 0); loadV(vr, 0);

    #pragma unroll 1
    for (int t = 0; t < 32; t++) {
        const int buf = t & 1;
        const int tn = (t + 1 < 32) ? t + 1 : 31;
        // ---- QK^T: S^T[16 keys of wave][64 q], 4 independent acc chains ----
        float4_t s0 = (float4_t)(0.f), s1 = (float4_t)(0.f);
        float4_t s2 = (float4_t)(0.f), s3 = (float4_t)(0.f);
        #pragma unroll
        for (int kb = 0; kb < 8; kb++) {
            s0 = __builtin_amdgcn_mfma_f32_16x16x32_bf16(kr[kb], th[0][kb], s0, 0, 0, 0);
            s1 = __builtin_amdgcn_mfma_f32_16x16x32_bf16(kr[kb], th[1][kb], s1, 0, 0, 0);
            s2 = __builtin_amdgcn_mfma_f32_16x16x32_bf16(kr[kb], th[2][kb], s2, 0, 0, 0);
            s3 = __builtin_amdgcn_mfma_f32_16x16x32_bf16(kr[kb], th[3][kb], s3, 0, 0, 0);
        }
        loadK(kr, tn);       // WAR-safe: QK(t) already consumed kr; lands during exp+PV
        // ---- exp, row-sum partials, pack to P relay (fragment-major) ----
        {
            float e0 = exp2f(s0[0] * SC), e1 = exp2f(s0[1] * SC);
            float e2 = exp2f(s0[2] * SC), e3 = exp2f(s0[3] * SC);
            lrow[0] += e0 + e1 + e2 + e3;
            short4_t pk = { (short)f2b(e0), (short)f2b(e1), (short)f2b(e2), (short)f2b(e3) };
            *(short4_t*)(&Pbuf[buf][0 * 2 + pfrag_k][pcell][poff]) = pk;
        }
        {
            float e0 = exp2f(s1[0] * SC), e1 = exp2f(s1[1] * SC);
            float e2 = exp2f(s1[2] * SC), e3 = exp2f(s1[3] * SC);
            lrow[1] += e0 + e1 + e2 + e3;
            short4_t pk = { (short)f2b(e0), (short)f2b(e1), (short)f2b(e2), (short)f2b(e3) };
            *(short4_t*)(&Pbuf[buf][1 * 2 + pfrag_k][pcell][poff]) = pk;
        }
        {
            float e0 = exp2f(s2[0] * SC), e1 = exp2f(s2[1] * SC);
            float e2 = exp2f(s2[2] * SC), e3 = exp2f(s2[3] * SC);
            lrow[2] += e0 + e1 + e2 + e3;
            short4_t pk = { (short)f2b(e0), (short)f2b(e1), (short)f2b(e2), (short)f2b(e3) };
            *(short4_t*)(&Pbuf[buf][2 * 2 + pfrag_k][pcell][poff]) = pk;
        }
        {
            float e0 = exp2f(s3[0] * SC), e1 = exp2f(s3[1] * SC);
            float e2 = exp2f(s3[2] * SC), e3 = exp2f(s3[3] * SC);
            lrow[3] += e0 + e1 + e2 + e3;
            short4_t pk = { (short)f2b(e0), (short)f2b(e1), (short)f2b(e2), (short)f2b(e3) };
            *(short4_t*)(&Pbuf[buf][3 * 2 + pfrag_k][pcell][poff]) = pk;
        }
        __syncthreads();                                  // P(t) complete
        // ---- PV: o[ch 64 of wave][q 64] += V * P ----
        short8 pf[8];
        #pragma unroll
        for (int f = 0; f < 8; f++)
            pf[f] = *(const short8*)(&Pbuf[buf][f][lane][0]);
        #pragma unroll
        for (int ct = 0; ct < 4; ct++)
            #pragma unroll
            for (int qt = 0; qt < 4; qt++)
                #pragma unroll
                for (int kst = 0; kst < 2; kst++)
                    o[ct][qt] = __builtin_amdgcn_mfma_f32_16x16x32_bf16(
                        vr[ct * 2 + kst], pf[qt * 2 + kst], o[ct][qt], 0, 0, 0);
        loadV(vr, tn);       // WAR-safe: PV(t) consumed vr; lands during next QK+exp
    }

    // ---- epilogue: reduce partial l across quads + waves, store partials ----
    #pragma unroll
    for (int qt = 0; qt < 4; qt++) {
        float v = lrow[qt];
        v += __shfl_xor(v, 16);
        v += __shfl_xor(v, 32);
        if (quad == 0) Lbuf[w][qt * 16 + nidx] = v;
    }
    __syncthreads();
    if (tid < 64)
        lw[(size_t)h * SEQ + seq0 + p0 + tid] =
            Lbuf[0][tid] + Lbuf[1][tid] + Lbuf[2][tid] + Lbuf[3][tid];
    // lane holds O[ch = w*64+ct*16+quad*4+r][q = qt*16+nidx]; store rows=q, cols=ch
    float* Op = Ow + ((size_t)h * SEQ + seq0 + p0) * CC;
    #pragma unroll
    for (int ct = 0; ct < 4; ct++)
        #pragma unroll
        for (int qt = 0; qt < 4; qt++)
            *(float4_t*)(Op + (size_t)(qt * 16 + nidx) * CC + w * 64 + ct * 16 + quad * 4) = o[ct][qt];
}

// ---- kernel 3b: combine key-halves: fT[q][ch] = (O0+O1)/(l0+l1) as bf16 ----
__global__ __launch_bounds__(256) void k_reduce(const float* __restrict__ Ow,
                                                const float* __restrict__ lw,
                                                unsigned short* __restrict__ fT) {
    const float4_t* O0 = (const float4_t*)Ow;
    const float4_t* O1 = (const float4_t*)(Ow + SEQ * CC);
    int i0 = blockIdx.x * 256 + threadIdx.x;             // grid 1024 x 4 iters
    #pragma unroll
    for (int j = 0; j < 4; j++) {
        int idx = j * 262144 + i0;                       // float4 index, SEQ*CC/4 total
        int row = idx >> 6;                              // 64 float4 per 256-ch row
        float li = 1.0f / (lw[row] + lw[SEQ + row]);
        float4_t a = O0[idx];
        float4_t b = O1[idx];
        short4_t pk;
        #pragma unroll
        for (int r = 0; r < 4; r++) pk[r] = (short)f2b((a[r] + b[r]) * li);
        *(short4_t*)(fT + (size_t)idx * 4) = pk;
    }
}

// ---- kernel 4: out[n][co][p] = x + b[co] + sum_k W[co][k]*fT[p][k] ----
__global__ __launch_bounds__(256) void k_final(const unsigned short* __restrict__ Wc,
                                               const float* __restrict__ bc,
                                               const unsigned short* __restrict__ fT,
                                               const float* __restrict__ x,
                                               float* __restrict__ out) {
    int w = threadIdx.x >> 6, lane = threadIdx.x & 63;
    int nidx = lane & 15, quad = lane >> 4;
    int n = blockIdx.z;
    int co0 = blockIdx.y * 64 + w * 16;
    int p0 = blockIdx.x * 64;
    float4_t acc[4];
    #pragma unroll
    for (int i = 0; i < 4; i++) acc[i] = (float4_t)(0.f);
    const unsigned short* arow = Wc + (size_t)(co0 + nidx) * CC + quad * 8;
    const unsigned short* brow = fT + ((size_t)n * HW + p0 + nidx) * CC + quad * 8;
    for (int ks = 0; ks < 8; ks++) {
        short8 a = *(const short8*)(arow + ks * 32);
        #pragma unroll
        for (int pb = 0; pb < 4; pb++) {
            short8 bb = *(const short8*)(brow + (size_t)pb * 16 * CC + ks * 32);
            acc[pb] = __builtin_amdgcn_mfma_f32_16x16x32_bf16(a, bb, acc[pb], 0, 0, 0);
        }
    }
    #pragma unroll
    for (int pb = 0; pb < 4; pb++) {
        #pragma unroll
        for (int r = 0; r < 4; r++) {
            int co = co0 + quad * 4 + r;
            size_t idx = ((size_t)n * CC + co) * HW + p0 + pb * 16 + nidx;
            out[idx] = x[idx] + bc[co] + acc[pb][r];
        }
    }
}

extern "C" void kernel_launch(void* const* d_in, const int* in_sizes, int n_in,
                              void* d_out, int out_size, void* d_ws, size_t ws_size,
                              hipStream_t stream) {
    const float* x       = (const float*)d_in[0];
    const float* theta_w = (const float*)d_in[1];
    const float* theta_b = (const float*)d_in[2];
    const float* phi_w   = (const float*)d_in[3];
    const float* phi_b   = (const float*)d_in[4];
    const float* conv1_w = (const float*)d_in[5];
    const float* conv1_b = (const float*)d_in[6];
    float* out = (float*)d_out;

    unsigned short* XT  = (unsigned short*)d_ws;  // [SEQ][256] bf16
    unsigned short* gb  = XT  + SEQ * CC;         // [N][256][4096]
    unsigned short* thT = gb  + SEQ * CC;         // [SEQ][256]
    unsigned short* phT = thT + SEQ * CC;         // [SEQ][256]
    unsigned short* fT  = phT + SEQ * CC;         // [SEQ][256]
    unsigned short* Wbt = fT  + SEQ * CC;
    unsigned short* Wbp = Wbt + 65536;
    unsigned short* Wbc = Wbp + 65536;
    float* Ow = (float*)(Wbc + 65536);            // [2][SEQ][256] fp32 partial O
    float* lw = Ow + 2 * SEQ * CC;                // [2][SEQ] fp32 partial l

    k_prep<<<dim3(64, 4, 4), 256, 0, stream>>>(x, theta_w, phi_w, conv1_w, XT, gb, Wbt, Wbp, Wbc);
    k_proj<<<dim3(256, 2), 256, 0, stream>>>(XT, Wbt, Wbp, theta_b, phi_b, thT, phT);
    k_attn<<<dim3(512), 256, 0, stream>>>(thT, phT, gb, Ow, lw);
    k_reduce<<<dim3(1024), 256, 0, stream>>>(Ow, lw, fT);
    k_final<<<dim3(64, 4, 4), 256, 0, stream>>>(Wbc, conv1_b, fT, x, out);
}